// Round 17
// baseline (13776.439 us; speedup 1.0000x reference)
//
#include <hip/hip_runtime.h>
#include <hip/hip_bf16.h>
#include <hip/hip_fp16.h>
#include <stdint.h>

#define K_NBR 32
#define EPS_F 1e-5f

typedef __hip_bfloat16 bf16;

template<typename T> struct VT;
template<> struct VT<float> {
    static __device__ __forceinline__ float ld(float v) { return v; }
    static __device__ __forceinline__ float st(float v) { return v; }
};
template<> struct VT<__half> {
    static __device__ __forceinline__ float  ld(__half v) { return __half2float(v); }
    static __device__ __forceinline__ __half st(float v) { return __float2half(v); }
};

// ---------------------------------------------------------------------------
// FPS: f32, all-rn ascending DIRECT form, smallest-index argmax. Verified
// exact (output 0 passes every round). DO NOT TOUCH.
// ---------------------------------------------------------------------------
template<int PPT>
__global__ __launch_bounds__(256) void fps_kernel(const float* __restrict__ p, int N, int S,
                                                  int* __restrict__ idx_out,
                                                  float* __restrict__ centers) {
    const int b = blockIdx.x;
    const int tid = threadIdx.x;
    const float* pb = p + (size_t)b * N * 3;

    float px[PPT], py[PPT], pz[PPT], dist[PPT];
    const float l0x = pb[0], l0y = pb[1], l0z = pb[2];
#pragma unroll
    for (int j = 0; j < PPT; ++j) {
        int i = j * 256 + tid;
        px[j] = pb[(size_t)i * 3 + 0];
        py[j] = pb[(size_t)i * 3 + 1];
        pz[j] = pb[(size_t)i * 3 + 2];
        float dx = __fsub_rn(px[j], l0x);
        float dy = __fsub_rn(py[j], l0y);
        float dz = __fsub_rn(pz[j], l0z);
        dist[j] = __fadd_rn(__fadd_rn(__fmul_rn(dx, dx), __fmul_rn(dy, dy)), __fmul_rn(dz, dz));
    }

    __shared__ float s_val[4];
    __shared__ int   s_idx[4];
    __shared__ int   s_bi;

    if (tid == 0) {
        idx_out[(size_t)b * S] = 0;
        centers[((size_t)b * S) * 3 + 0] = l0x;
        centers[((size_t)b * S) * 3 + 1] = l0y;
        centers[((size_t)b * S) * 3 + 2] = l0z;
    }

    for (int t = 1; t < S; ++t) {
        float bv = dist[0];
        int bi = tid;
#pragma unroll
        for (int j = 1; j < PPT; ++j) {
            if (dist[j] > bv) { bv = dist[j]; bi = j * 256 + tid; }
        }
#pragma unroll
        for (int off = 32; off >= 1; off >>= 1) {
            float ov = __shfl_down(bv, off);
            int   oi = __shfl_down(bi, off);
            if (ov > bv || (ov == bv && oi < bi)) { bv = ov; bi = oi; }
        }
        int wid = tid >> 6;
        if ((tid & 63) == 0) { s_val[wid] = bv; s_idx[wid] = bi; }
        __syncthreads();
        if (tid == 0) {
            bv = s_val[0]; bi = s_idx[0];
            for (int w = 1; w < 4; ++w)
                if (s_val[w] > bv || (s_val[w] == bv && s_idx[w] < bi)) { bv = s_val[w]; bi = s_idx[w]; }
            s_bi = bi;
            idx_out[(size_t)b * S + t] = bi;
        }
        __syncthreads();
        bi = s_bi;
        const float lx = pb[(size_t)bi * 3 + 0];
        const float ly = pb[(size_t)bi * 3 + 1];
        const float lz = pb[(size_t)bi * 3 + 2];
        if (tid == 0) {
            centers[((size_t)b * S + t) * 3 + 0] = lx;
            centers[((size_t)b * S + t) * 3 + 1] = ly;
            centers[((size_t)b * S + t) * 3 + 2] = lz;
        }
#pragma unroll
        for (int j = 0; j < PPT; ++j) {
            float dx = __fsub_rn(px[j], lx);
            float dy = __fsub_rn(py[j], ly);
            float dz = __fsub_rn(pz[j], lz);
            float nd = __fadd_rn(__fadd_rn(__fmul_rn(dx, dx), __fmul_rn(dy, dy)), __fmul_rn(dz, dz));
            dist[j] = fminf(dist[j], nd);
        }
    }
}

// ---------------------------------------------------------------------------
// Ball query — shared-einsum SIMD-partial-load hypothesis: ALL THREE
// contractions use the npyv_load_tillz + muladd + horizontal-sum lowering.
// For count=3 the lanes are [t0,t1,t2,0] and the x86 reduce tree computes
// (t0 + t2) + (t1 + 0):
//   cn = rn(rn(c0^2 + c2^2) + c1^2)
//   pn = rn(rn(x^2  + z^2 ) + y^2 )
//   dt = rn(rn(p0   + p2  ) + p1 )   (products individually rounded)
// Outer (confirmed by R15): d2 = rn(rn(cn+pn) - 2*dt); R2 = f32(0.01).
// ---------------------------------------------------------------------------
__global__ __launch_bounds__(256) void ball_query_kernel(const float* __restrict__ pts,
                                                         const float* __restrict__ ctr,
                                                         int N, int S, int* __restrict__ nbr) {
    int gw   = (int)((blockIdx.x * 256 + threadIdx.x) >> 6);
    int lane = threadIdx.x & 63;
    int b = gw / S;
    int s = gw - b * S;
    const float* pb = pts + (size_t)b * N * 3;
    const float c0 = ctr[((size_t)b * S + s) * 3 + 0];
    const float c1 = ctr[((size_t)b * S + s) * 3 + 1];
    const float c2 = ctr[((size_t)b * S + s) * 3 + 2];
    // horizontal-SIMD grouping: (c0^2 + c2^2) + c1^2
    const float cn = __fadd_rn(__fadd_rn(__fmul_rn(c0, c0), __fmul_rn(c2, c2)), __fmul_rn(c1, c1));
    const float R2 = (float)(0.1 * 0.1);
    int* out = nbr + (size_t)gw * K_NBR;

    int cnt = 0;
    int firstIdx = 0;
    bool haveFirst = false;
    for (int base = 0; base < N && cnt < K_NBR; base += 64) {
        int i = base + lane;
        float x = pb[(size_t)i * 3 + 0];
        float y = pb[(size_t)i * 3 + 1];
        float z = pb[(size_t)i * 3 + 2];
        // horizontal-SIMD grouping: (x^2 + z^2) + y^2
        float pn = __fadd_rn(__fadd_rn(__fmul_rn(x, x), __fmul_rn(z, z)), __fmul_rn(y, y));
        // horizontal-SIMD dot: (p0 + p2) + p1
        float pr0 = __fmul_rn(c0, x);
        float pr1 = __fmul_rn(c1, y);
        float pr2 = __fmul_rn(c2, z);
        float dt  = __fadd_rn(__fadd_rn(pr0, pr2), pr1);
        float d2 = __fsub_rn(__fadd_rn(cn, pn), __fmul_rn(2.0f, dt));
        bool inR = d2 < R2;
        unsigned long long mask = __ballot(inR);
        if (mask) {
            if (!haveFirst) { haveFirst = true; firstIdx = base + __builtin_ctzll(mask); }
            int rank = __popcll(mask & ((1ull << lane) - 1ull));
            if (inR) {
                int slot = cnt + rank;
                if (slot < K_NBR) out[slot] = i;
            }
            cnt += (int)__popcll(mask);
        }
    }
    if (cnt < K_NBR) {
        for (int sl = cnt + lane; sl < K_NBR; sl += 64) out[sl] = firstIdx;
    }
}

// ---------------------------------------------------------------------------
// Per-batch conv pipeline, storage T = __half.
// ---------------------------------------------------------------------------
__global__ void gather_cf_kernel(const float* __restrict__ f_b, const int* __restrict__ idx_b,
                                 int N, int S, float* __restrict__ cf, int total) {
    int i = blockIdx.x * 256 + threadIdx.x;
    if (i >= total) return;
    int s = i % S;
    int c = i / S;
    cf[i] = f_b[(size_t)c * N + idx_b[s]];
}

template<typename T>
__global__ void build_x_kernel(const float* __restrict__ p_b, const float* __restrict__ f_b,
                               const float* __restrict__ ctr_b, const float* __restrict__ cf,
                               const int* __restrict__ nbr_b,
                               int N, int S, int C, int M, T* __restrict__ x) {
    int m = blockIdx.x * 256 + threadIdx.x;
    if (m >= M) return;
    int s = m / K_NBR;
    int n = nbr_b[m];
    const float* pp = p_b + (size_t)n * 3;
    const float* cc = ctr_b + (size_t)s * 3;
    x[(size_t)0 * M + m] = VT<T>::st(__fsub_rn(pp[0], cc[0]));
    x[(size_t)1 * M + m] = VT<T>::st(__fsub_rn(pp[1], cc[1]));
    x[(size_t)2 * M + m] = VT<T>::st(__fsub_rn(pp[2], cc[2]));
    for (int c = 0; c < C; ++c) {
        float v = __fsub_rn(f_b[(size_t)c * N + n], cf[(size_t)c * S + s]);
        x[(size_t)(3 + c) * M + m] = VT<T>::st(v);
    }
}

template<typename T>
__global__ __launch_bounds__(256) void conv_gemm_kernel(
    const float* __restrict__ W, const float* __restrict__ bias, int Ctot, int C1,
    const T* __restrict__ X1, const T* __restrict__ X2,
    T* __restrict__ Y, int M) {
    int m0 = blockIdx.x * 512 + threadIdx.x;
    int m1 = m0 + 256;
    int o0 = blockIdx.y * 16;
    float acc0[16], acc1[16];
#pragma unroll
    for (int i = 0; i < 16; ++i) { float bv = bias[o0 + i]; acc0[i] = bv; acc1[i] = bv; }
    const float* Wr = W + (size_t)o0 * Ctot;

    if (C1 > 0) {
        int P  = M / K_NBR;
        int p0 = m0 / K_NBR;
        int p1 = m1 / K_NBR;
        for (int c = 0; c < C1; ++c) {
            float x0 = VT<T>::ld(X1[(size_t)c * P + p0]);
            float x1 = VT<T>::ld(X1[(size_t)c * P + p1]);
#pragma unroll
            for (int i = 0; i < 16; ++i) {
                float w = Wr[(size_t)i * Ctot + c];
                acc0[i] = fmaf(w, x0, acc0[i]);
                acc1[i] = fmaf(w, x1, acc1[i]);
            }
        }
    }
    int C2 = Ctot - C1;
    const float* Wr2 = Wr + C1;
    for (int c = 0; c < C2; ++c) {
        float x0 = VT<T>::ld(X2[(size_t)c * M + m0]);
        float x1 = VT<T>::ld(X2[(size_t)c * M + m1]);
#pragma unroll
        for (int i = 0; i < 16; ++i) {
            float w = Wr2[(size_t)i * Ctot + c];
            acc0[i] = fmaf(w, x0, acc0[i]);
            acc1[i] = fmaf(w, x1, acc1[i]);
        }
    }
#pragma unroll
    for (int i = 0; i < 16; ++i) {
        Y[(size_t)(o0 + i) * M + m0] = VT<T>::st(acc0[i]);
        Y[(size_t)(o0 + i) * M + m1] = VT<T>::st(acc1[i]);
    }
}

// Two-pass InstanceNorm stats (jnp.var algorithm).
template<typename T>
__global__ __launch_bounds__(256) void in_stats_kernel(const T* __restrict__ Y, int M,
                                                       float* __restrict__ mean,
                                                       float* __restrict__ rinv) {
    int o = blockIdx.x;
    const T* row = Y + (size_t)o * M;
    int tid = threadIdx.x;
    __shared__ float sS[4];
    __shared__ float s_mu;

    float s = 0.f;
    for (int j = tid; j < M; j += 256) s += VT<T>::ld(row[j]);
#pragma unroll
    for (int off = 32; off >= 1; off >>= 1) s += __shfl_down(s, off);
    if ((tid & 63) == 0) sS[tid >> 6] = s;
    __syncthreads();
    if (tid == 0) s_mu = (sS[0] + sS[1] + sS[2] + sS[3]) / (float)M;
    __syncthreads();
    float mu = s_mu;

    float q = 0.f;
    for (int j = tid; j < M; j += 256) {
        float d = VT<T>::ld(row[j]) - mu;
        q = fmaf(d, d, q);
    }
#pragma unroll
    for (int off = 32; off >= 1; off >>= 1) q += __shfl_down(q, off);
    if ((tid & 63) == 0) sS[tid >> 6] = q;
    __syncthreads();
    if (tid == 0) {
        float var = (sS[0] + sS[1] + sS[2] + sS[3]) / (float)M;
        mean[o] = mu;
        rinv[o] = rsqrtf(var + EPS_F);
    }
}

template<typename T>
__global__ void in_apply_kernel(T* __restrict__ Y, int M,
                                const float* __restrict__ mean, const float* __restrict__ rinv) {
    int o = blockIdx.y;
    int col = blockIdx.x * 256 + threadIdx.x;
    size_t i = (size_t)o * M + col;
    float v = VT<T>::ld(Y[i]);
    v = (v - mean[o]) * rinv[o];
    Y[i] = VT<T>::st(fmaxf(v, 0.f));
}

template<typename T>
__global__ void maxk_kernel(const T* __restrict__ Y, T* __restrict__ pooled, int total) {
    int i = blockIdx.x * 256 + threadIdx.x;
    if (i >= total) return;
    const T* src = Y + (size_t)i * K_NBR;
    float mx = VT<T>::ld(src[0]);
#pragma unroll
    for (int k = 1; k < K_NBR; ++k) mx = fmaxf(mx, VT<T>::ld(src[k]));
    pooled[i] = VT<T>::st(mx);
}

template<typename T>
__global__ void maxk_out_kernel(const T* __restrict__ Y, int S, float* __restrict__ outf_b,
                                int total) {
    int i = blockIdx.x * 256 + threadIdx.x;
    if (i >= total) return;
    const T* src = Y + (size_t)i * K_NBR;   // i = o*S + s, row stride M = S*K
    float mx = VT<T>::ld(src[0]);
#pragma unroll
    for (int k = 1; k < K_NBR; ++k) mx = fmaxf(mx, VT<T>::ld(src[k]));
    outf_b[i] = mx;
}

// ---------------------------------------------------------------------------
struct StageArgs {
    const float *P, *F, *CTR;
    const int *NBR, *IDX;
    int N, S, C, e;
    const float *Wa1, *ba1, *Wb1, *bb1, *Wa2, *ba2, *Wb2, *bb2;
    float* OUTF;
};

template<typename T>
static void run_conv_stage(const StageArgs& a, hipStream_t stream,
                           uint8_t* R1, uint8_t* R2, size_t xo_off,
                           T* pooled, float* cf_ws, float* mean_ws, float* rinv_ws) {
    const int M = a.S * K_NBR;
    T* x0 = (T*)R1;
    T* RA = (T*)(R1 + xo_off);   // conv1a out
    T* RC = (T*)R1;              // conv2a out (x0/RA dead by then)
    T* RB = (T*)R2;              // conv1b out
    T* RD = (T*)R2;              // conv2b out (RB dead by then)
    for (int b = 0; b < 4; ++b) {
        const float* p_b   = a.P + (size_t)b * a.N * 3;
        const float* f_b   = a.F + (size_t)b * a.C * a.N;
        const float* ctr_b = a.CTR + (size_t)b * a.S * 3;
        const int*   nbr_b = a.NBR + (size_t)b * a.S * K_NBR;
        const int*   idx_b = a.IDX + (size_t)b * a.S;
        float*       outf_b= a.OUTF + (size_t)b * a.e * a.S;

        gather_cf_kernel<<<(a.C * a.S + 255) / 256, 256, 0, stream>>>(f_b, idx_b, a.N, a.S, cf_ws, a.C * a.S);
        build_x_kernel<T><<<M / 256, 256, 0, stream>>>(p_b, f_b, ctr_b, cf_ws, nbr_b, a.N, a.S, a.C, M, x0);

        dim3 g1(M / 512, a.e / 16);
        conv_gemm_kernel<T><<<g1, 256, 0, stream>>>(a.Wa1, a.ba1, a.C + 3, 0, nullptr, x0, RA, M);
        in_stats_kernel<T><<<a.e, 256, 0, stream>>>(RA, M, mean_ws, rinv_ws);
        in_apply_kernel<T><<<dim3(M / 256, a.e), 256, 0, stream>>>(RA, M, mean_ws, rinv_ws);

        conv_gemm_kernel<T><<<g1, 256, 0, stream>>>(a.Wb1, a.bb1, a.e, 0, nullptr, RA, RB, M);
        maxk_kernel<T><<<(a.e * a.S + 255) / 256, 256, 0, stream>>>(RB, pooled, a.e * a.S);

        dim3 g2(M / 512, (2 * a.e) / 16);
        conv_gemm_kernel<T><<<g2, 256, 0, stream>>>(a.Wa2, a.ba2, 2 * a.e, a.e, pooled, RB, RC, M);
        in_stats_kernel<T><<<2 * a.e, 256, 0, stream>>>(RC, M, mean_ws, rinv_ws);
        in_apply_kernel<T><<<dim3(M / 256, 2 * a.e), 256, 0, stream>>>(RC, M, mean_ws, rinv_ws);

        conv_gemm_kernel<T><<<g1, 256, 0, stream>>>(a.Wb2, a.bb2, 2 * a.e, 0, nullptr, RC, RD, M);
        in_stats_kernel<T><<<a.e, 256, 0, stream>>>(RD, M, mean_ws, rinv_ws);
        in_apply_kernel<T><<<dim3(M / 256, a.e), 256, 0, stream>>>(RD, M, mean_ws, rinv_ws);

        maxk_out_kernel<T><<<(a.e * a.S + 255) / 256, 256, 0, stream>>>(RD, a.S, outf_b, a.e * a.S);
    }
}

extern "C" void kernel_launch(void* const* d_in, const int* in_sizes, int n_in,
                              void* d_out, int out_size, void* d_ws, size_t ws_size,
                              hipStream_t stream) {
    const float* p    = (const float*)d_in[0];
    const float* f    = (const float*)d_in[1];
    const float* w1a1 = (const float*)d_in[2];
    const float* b1a1 = (const float*)d_in[3];
    const float* w1b1 = (const float*)d_in[4];
    const float* b1b1 = (const float*)d_in[5];
    const float* w1a2 = (const float*)d_in[6];
    const float* b1a2 = (const float*)d_in[7];
    const float* w1b2 = (const float*)d_in[8];
    const float* b1b2 = (const float*)d_in[9];
    const float* w2a1 = (const float*)d_in[10];
    const float* b2a1 = (const float*)d_in[11];
    const float* w2b1 = (const float*)d_in[12];
    const float* b2b1 = (const float*)d_in[13];
    const float* w2a2 = (const float*)d_in[14];
    const float* b2a2 = (const float*)d_in[15];
    const float* w2b2 = (const float*)d_in[16];
    const float* b2b2 = (const float*)d_in[17];

    float* out   = (float*)d_out;
    float* outp1 = out;                       // (4,2048,3)   = 24576
    float* outf1 = out + 24576;               // (4,192,2048) = 1572864
    float* outp2 = outf1 + 1572864;           // (4,512,3)    = 6144
    float* outf2 = outp2 + 6144;              // (4,384,512)  = 786432

    uint8_t* wsp = (uint8_t*)d_ws;
    uint8_t* wend = wsp + ws_size;
    auto alloc = [&](size_t bytes) -> void* {
        void* r = wsp;
        wsp += (bytes + 255) & ~(size_t)255;
        return r;
    };
    int*   idx1   = (int*)  alloc((size_t)4 * 2048 * 4);
    int*   idx2   = (int*)  alloc((size_t)4 * 512 * 4);
    int*   nbr1   = (int*)  alloc((size_t)4 * 2048 * K_NBR * 4);
    int*   nbr2   = (int*)  alloc((size_t)4 * 512 * K_NBR * 4);
    float* cf_ws  = (float*)alloc((size_t)192 * 512 * 4);
    float* mean_ws= (float*)alloc((size_t)768 * 4);
    float* rinv_ws= (float*)alloc((size_t)768 * 4);
    __half* pooled = (__half*)alloc((size_t)192 * 2048 * 2);
    if (wsp > wend) return;

    // geometry: asc-rn FPS (verified); BQ all-horizontal-SIMD contractions
    fps_kernel<32><<<4, 256, 0, stream>>>(p, 8192, 2048, idx1, outp1);
    ball_query_kernel<<<(4 * 2048) / 4, 256, 0, stream>>>(p, outp1, 8192, 2048, nbr1);
    fps_kernel<8><<<4, 256, 0, stream>>>(outp1, 2048, 512, idx2, outp2);
    ball_query_kernel<<<(4 * 512) / 4, 256, 0, stream>>>(outp1, outp2, 2048, 512, nbr2);

    const size_t MB = (size_t)1024 * 1024;
    uint8_t* R1 = (uint8_t*)alloc(48 * MB);
    uint8_t* R2 = (uint8_t*)alloc(24 * MB);
    if (wsp > wend) return;

    StageArgs s1 { p, f, outp1, nbr1, idx1, 8192, 2048, 3, 192,
                   w1a1, b1a1, w1b1, b1b1, w1a2, b1a2, w1b2, b1b2, outf1 };
    StageArgs s2 { outp1, outf1, outp2, nbr2, idx2, 2048, 512, 192, 384,
                   w2a1, b2a1, w2b1, b2b1, w2a2, b2a2, w2b2, b2b2, outf2 };

    run_conv_stage<__half>(s1, stream, R1, R2, 8 * MB, pooled, cf_ws, mean_ws, rinv_ws);
    run_conv_stage<__half>(s2, stream, R1, R2, 8 * MB, pooled, cf_ws, mean_ws, rinv_ws);
}

// Round 18
// 10031.585 us; speedup vs baseline: 1.3733x; 1.3733x over previous
//
#include <hip/hip_runtime.h>
#include <hip/hip_bf16.h>
#include <hip/hip_fp16.h>
#include <stdint.h>

#define K_NBR 32
#define EPS_F 1e-5f

// ---------------------------------------------------------------------------
// FPS: EXACT arithmetic as the verified version (asc-rn direct form, smallest-
// index argmax). Structural speedups only: 4 independent local-scan chains
// (merge order preserves smallest-index ties), single __syncthreads per step
// via double-buffered LDS slots, all-thread final reduce (no thread0 serial).
// ---------------------------------------------------------------------------
template<int PPT>
__global__ __launch_bounds__(256) void fps_kernel(const float* __restrict__ p, int N, int S,
                                                  int* __restrict__ idx_out,
                                                  float* __restrict__ centers) {
    const int b = blockIdx.x;
    const int tid = threadIdx.x;
    const float* pb = p + (size_t)b * N * 3;

    float px[PPT], py[PPT], pz[PPT], dist[PPT];
    const float l0x = pb[0], l0y = pb[1], l0z = pb[2];
#pragma unroll
    for (int j = 0; j < PPT; ++j) {
        int i = j * 256 + tid;
        px[j] = pb[(size_t)i * 3 + 0];
        py[j] = pb[(size_t)i * 3 + 1];
        pz[j] = pb[(size_t)i * 3 + 2];
        float dx = __fsub_rn(px[j], l0x);
        float dy = __fsub_rn(py[j], l0y);
        float dz = __fsub_rn(pz[j], l0z);
        dist[j] = __fadd_rn(__fadd_rn(__fmul_rn(dx, dx), __fmul_rn(dy, dy)), __fmul_rn(dz, dz));
    }

    __shared__ float s_val[2][4];
    __shared__ int   s_idx[2][4];

    if (tid == 0) {
        idx_out[(size_t)b * S] = 0;
        centers[((size_t)b * S) * 3 + 0] = l0x;
        centers[((size_t)b * S) * 3 + 1] = l0y;
        centers[((size_t)b * S) * 3 + 2] = l0z;
    }

    constexpr int CH = PPT / 4;
    for (int t = 1; t < S; ++t) {
        const int pp = t & 1;
        // 4 independent ascending chains ('>' keeps first = smallest index)
        float v[4]; int ix[4];
#pragma unroll
        for (int k = 0; k < 4; ++k) {
            v[k] = dist[k * CH]; ix[k] = (k * CH) * 256 + tid;
#pragma unroll
            for (int j = 1; j < CH; ++j) {
                if (dist[k * CH + j] > v[k]) { v[k] = dist[k * CH + j]; ix[k] = (k * CH + j) * 256 + tid; }
            }
        }
        // merge in chain order: chain k's indices all < chain k+1's (same tid)
        float bv = v[0]; int bi = ix[0];
#pragma unroll
        for (int k = 1; k < 4; ++k) if (v[k] > bv) { bv = v[k]; bi = ix[k]; }
        // wave argmax (max value, min index tiebreak)
#pragma unroll
        for (int off = 32; off >= 1; off >>= 1) {
            float ov = __shfl_down(bv, off);
            int   oi = __shfl_down(bi, off);
            if (ov > bv || (ov == bv && oi < bi)) { bv = ov; bi = oi; }
        }
        if ((tid & 63) == 0) { s_val[pp][tid >> 6] = bv; s_idx[pp][tid >> 6] = bi; }
        __syncthreads();
        // all threads do the 4-way final reduce (identical semantics)
        bv = s_val[pp][0]; bi = s_idx[pp][0];
#pragma unroll
        for (int w = 1; w < 4; ++w)
            if (s_val[pp][w] > bv || (s_val[pp][w] == bv && s_idx[pp][w] < bi)) { bv = s_val[pp][w]; bi = s_idx[pp][w]; }
        const float lx = pb[(size_t)bi * 3 + 0];
        const float ly = pb[(size_t)bi * 3 + 1];
        const float lz = pb[(size_t)bi * 3 + 2];
        if (tid == 0) {
            idx_out[(size_t)b * S + t] = bi;
            centers[((size_t)b * S + t) * 3 + 0] = lx;
            centers[((size_t)b * S + t) * 3 + 1] = ly;
            centers[((size_t)b * S + t) * 3 + 2] = lz;
        }
#pragma unroll
        for (int j = 0; j < PPT; ++j) {
            float dx = __fsub_rn(px[j], lx);
            float dy = __fsub_rn(py[j], ly);
            float dz = __fsub_rn(pz[j], lz);
            float nd = __fadd_rn(__fadd_rn(__fmul_rn(dx, dx), __fmul_rn(dy, dy)), __fmul_rn(dz, dz));
            dist[j] = fminf(dist[j], nd);
        }
    }
}

// ---------------------------------------------------------------------------
// Ball query — BYTE-IDENTICAL to the passing round 17 kernel. DO NOT TOUCH.
// ---------------------------------------------------------------------------
__global__ __launch_bounds__(256) void ball_query_kernel(const float* __restrict__ pts,
                                                         const float* __restrict__ ctr,
                                                         int N, int S, int* __restrict__ nbr) {
    int gw   = (int)((blockIdx.x * 256 + threadIdx.x) >> 6);
    int lane = threadIdx.x & 63;
    int b = gw / S;
    int s = gw - b * S;
    const float* pb = pts + (size_t)b * N * 3;
    const float c0 = ctr[((size_t)b * S + s) * 3 + 0];
    const float c1 = ctr[((size_t)b * S + s) * 3 + 1];
    const float c2 = ctr[((size_t)b * S + s) * 3 + 2];
    const float cn = __fadd_rn(__fadd_rn(__fmul_rn(c0, c0), __fmul_rn(c2, c2)), __fmul_rn(c1, c1));
    const float R2 = (float)(0.1 * 0.1);
    int* out = nbr + (size_t)gw * K_NBR;

    int cnt = 0;
    int firstIdx = 0;
    bool haveFirst = false;
    for (int base = 0; base < N && cnt < K_NBR; base += 64) {
        int i = base + lane;
        float x = pb[(size_t)i * 3 + 0];
        float y = pb[(size_t)i * 3 + 1];
        float z = pb[(size_t)i * 3 + 2];
        float pn = __fadd_rn(__fadd_rn(__fmul_rn(x, x), __fmul_rn(z, z)), __fmul_rn(y, y));
        float pr0 = __fmul_rn(c0, x);
        float pr1 = __fmul_rn(c1, y);
        float pr2 = __fmul_rn(c2, z);
        float dt  = __fadd_rn(__fadd_rn(pr0, pr2), pr1);
        float d2 = __fsub_rn(__fadd_rn(cn, pn), __fmul_rn(2.0f, dt));
        bool inR = d2 < R2;
        unsigned long long mask = __ballot(inR);
        if (mask) {
            if (!haveFirst) { haveFirst = true; firstIdx = base + __builtin_ctzll(mask); }
            int rank = __popcll(mask & ((1ull << lane) - 1ull));
            if (inR) {
                int slot = cnt + rank;
                if (slot < K_NBR) out[slot] = i;
            }
            cnt += (int)__popcll(mask);
        }
    }
    if (cnt < K_NBR) {
        for (int sl = cnt + lane; sl < K_NBR; sl += 64) out[sl] = firstIdx;
    }
}

// ---------------------------------------------------------------------------
__global__ void gather_cf_kernel(const float* __restrict__ f_b, const int* __restrict__ idx_b,
                                 int N, int S, float* __restrict__ cf, int total) {
    int i = blockIdx.x * 256 + threadIdx.x;
    if (i >= total) return;
    int s = i % S;
    int c = i / S;
    cf[i] = f_b[(size_t)c * N + idx_b[s]];
}

__global__ void build_x_kernel(const float* __restrict__ p_b, const float* __restrict__ f_b,
                               const float* __restrict__ ctr_b, const float* __restrict__ cf,
                               const int* __restrict__ nbr_b,
                               int N, int S, int C, int M, __half* __restrict__ x) {
    int m = blockIdx.x * 256 + threadIdx.x;
    if (m >= M) return;
    int s = m / K_NBR;
    int n = nbr_b[m];
    const float* pp = p_b + (size_t)n * 3;
    const float* cc = ctr_b + (size_t)s * 3;
    x[(size_t)0 * M + m] = __float2half(__fsub_rn(pp[0], cc[0]));
    x[(size_t)1 * M + m] = __float2half(__fsub_rn(pp[1], cc[1]));
    x[(size_t)2 * M + m] = __float2half(__fsub_rn(pp[2], cc[2]));
    for (int c = 0; c < C; ++c) {
        float v = __fsub_rn(f_b[(size_t)c * N + n], cf[(size_t)c * S + s]);
        x[(size_t)(3 + c) * M + m] = __float2half(v);
    }
}

// ---------------------------------------------------------------------------
// Conv GEMM: 2 adjacent columns per thread (half2 loads), 16 out-ch,
// unroll-4 c loop for 4 loads in flight. Pooled C1 value is shared by
// the column pair (both columns map to the same pooled index).
// ---------------------------------------------------------------------------
__global__ __launch_bounds__(256) void conv_gemm_kernel(
    const float* __restrict__ W, const float* __restrict__ bias, int Ctot, int C1,
    const __half* __restrict__ X1, const __half* __restrict__ X2,
    __half* __restrict__ Y, int M) {
    const int tid = threadIdx.x;
    const int col = blockIdx.x * 512 + 2 * tid;          // even column
    const int o0  = blockIdx.y * 16;
    const __half2* Xv = (const __half2*)X2;
    const int Mh = M >> 1;

    float a0[16], a1[16];
#pragma unroll
    for (int i = 0; i < 16; ++i) { float bv = bias[o0 + i]; a0[i] = bv; a1[i] = bv; }
    const float* Wr = W + (size_t)o0 * Ctot;

    if (C1 > 0) {
        int P  = M / K_NBR;
        int p0 = col >> 5;                                // same for both cols
        for (int c = 0; c < C1; ++c) {
            float x = __half2float(X1[(size_t)c * P + p0]);
#pragma unroll
            for (int i = 0; i < 16; ++i) {
                float w = Wr[(size_t)i * Ctot + c];
                a0[i] = fmaf(w, x, a0[i]);
                a1[i] = fmaf(w, x, a1[i]);
            }
        }
    }
    int C2 = Ctot - C1;
    const float* Wr2 = Wr + C1;
#pragma unroll 4
    for (int c = 0; c < C2; ++c) {
        float2 xf = __half22float2(Xv[(size_t)c * Mh + (col >> 1)]);
#pragma unroll
        for (int i = 0; i < 16; ++i) {
            float w = Wr2[(size_t)i * Ctot + c];
            a0[i] = fmaf(w, xf.x, a0[i]);
            a1[i] = fmaf(w, xf.y, a1[i]);
        }
    }
    __half2* Yv = (__half2*)Y;
#pragma unroll
    for (int i = 0; i < 16; ++i) {
        Yv[((size_t)(o0 + i) * M + col) >> 1] =
            __float22half2_rn(make_float2(a0[i], a1[i]));
    }
}

// ---------------------------------------------------------------------------
// Two-pass InstanceNorm stats, uint4 (8-half) vector loads.
// ---------------------------------------------------------------------------
__global__ __launch_bounds__(256) void in_stats_kernel(const __half* __restrict__ Y, int M,
                                                       float* __restrict__ mean,
                                                       float* __restrict__ rinv) {
    int o = blockIdx.x;
    const uint4* rv = (const uint4*)(Y + (size_t)o * M);
    int tid = threadIdx.x;
    int n8 = M >> 3;
    __shared__ float sS[4];
    __shared__ float s_mu;

    float s = 0.f;
    for (int j = tid; j < n8; j += 256) {
        uint4 v = rv[j];
        const __half2* h = (const __half2*)&v;
#pragma unroll
        for (int q = 0; q < 4; ++q) { float2 f = __half22float2(h[q]); s += f.x + f.y; }
    }
#pragma unroll
    for (int off = 32; off >= 1; off >>= 1) s += __shfl_down(s, off);
    if ((tid & 63) == 0) sS[tid >> 6] = s;
    __syncthreads();
    if (tid == 0) s_mu = (sS[0] + sS[1] + sS[2] + sS[3]) / (float)M;
    __syncthreads();
    float mu = s_mu;

    float q2 = 0.f;
    for (int j = tid; j < n8; j += 256) {
        uint4 v = rv[j];
        const __half2* h = (const __half2*)&v;
#pragma unroll
        for (int q = 0; q < 4; ++q) {
            float2 f = __half22float2(h[q]);
            float d0 = f.x - mu, d1 = f.y - mu;
            q2 = fmaf(d0, d0, q2);
            q2 = fmaf(d1, d1, q2);
        }
    }
#pragma unroll
    for (int off = 32; off >= 1; off >>= 1) q2 += __shfl_down(q2, off);
    if ((tid & 63) == 0) sS[tid >> 6] = q2;
    __syncthreads();
    if (tid == 0) {
        float var = (sS[0] + sS[1] + sS[2] + sS[3]) / (float)M;
        mean[o] = mu;
        rinv[o] = rsqrtf(var + EPS_F);
    }
}

__global__ void in_apply_kernel(__half* __restrict__ Y, int M,
                                const float* __restrict__ mean, const float* __restrict__ rinv) {
    int o = blockIdx.y;
    int col = blockIdx.x * 512 + 2 * threadIdx.x;
    float mu = mean[o], ri = rinv[o];
    __half2* Yv = (__half2*)Y;
    size_t idx = ((size_t)o * M + col) >> 1;
    float2 f = __half22float2(Yv[idx]);
    f.x = fmaxf((f.x - mu) * ri, 0.f);
    f.y = fmaxf((f.y - mu) * ri, 0.f);
    Yv[idx] = __float22half2_rn(f);
}

// pooled[i] = max over 32 consecutive halves (vectorized 4x uint4)
__global__ void maxk_kernel(const __half* __restrict__ Y, __half* __restrict__ pooled, int total) {
    int i = blockIdx.x * 256 + threadIdx.x;
    if (i >= total) return;
    const uint4* src = (const uint4*)(Y + (size_t)i * K_NBR);
    float mx = -3.0e38f;
#pragma unroll
    for (int q = 0; q < 4; ++q) {
        uint4 v = src[q];
        const __half2* h = (const __half2*)&v;
#pragma unroll
        for (int r = 0; r < 4; ++r) {
            float2 f = __half22float2(h[r]);
            mx = fmaxf(mx, fmaxf(f.x, f.y));
        }
    }
    pooled[i] = __float2half(mx);
}

// Fused IN + ReLU + max-pool for the final conv2b output:
// relu((max_k v - mu) * rinv) == max_k relu((v-mu)*rinv)  (rinv > 0, monotone)
__global__ void maxk_out_in_kernel(const __half* __restrict__ Y, int S,
                                   const float* __restrict__ mean, const float* __restrict__ rinv,
                                   float* __restrict__ outf_b, int total) {
    int i = blockIdx.x * 256 + threadIdx.x;
    if (i >= total) return;
    int o = i / S;
    const uint4* src = (const uint4*)(Y + (size_t)i * K_NBR);
    float mx = -3.0e38f;
#pragma unroll
    for (int q = 0; q < 4; ++q) {
        uint4 v = src[q];
        const __half2* h = (const __half2*)&v;
#pragma unroll
        for (int r = 0; r < 4; ++r) {
            float2 f = __half22float2(h[r]);
            mx = fmaxf(mx, fmaxf(f.x, f.y));
        }
    }
    outf_b[i] = fmaxf((mx - mean[o]) * rinv[o], 0.f);
}

// ---------------------------------------------------------------------------
struct StageArgs {
    const float *P, *F, *CTR;
    const int *NBR, *IDX;
    int N, S, C, e;
    const float *Wa1, *ba1, *Wb1, *bb1, *Wa2, *ba2, *Wb2, *bb2;
    float* OUTF;
};

static void run_conv_stage(const StageArgs& a, hipStream_t stream,
                           uint8_t* R1, uint8_t* R2, size_t xo_off,
                           __half* pooled, float* cf_ws, float* mean_ws, float* rinv_ws) {
    const int M = a.S * K_NBR;
    __half* x0 = (__half*)R1;
    __half* RA = (__half*)(R1 + xo_off);   // conv1a out
    __half* RC = (__half*)R1;              // conv2a out (x0/RA dead by then)
    __half* RB = (__half*)R2;              // conv1b out
    __half* RD = (__half*)R2;              // conv2b out (RB dead by then)
    for (int b = 0; b < 4; ++b) {
        const float* p_b   = a.P + (size_t)b * a.N * 3;
        const float* f_b   = a.F + (size_t)b * a.C * a.N;
        const float* ctr_b = a.CTR + (size_t)b * a.S * 3;
        const int*   nbr_b = a.NBR + (size_t)b * a.S * K_NBR;
        const int*   idx_b = a.IDX + (size_t)b * a.S;
        float*       outf_b= a.OUTF + (size_t)b * a.e * a.S;

        gather_cf_kernel<<<(a.C * a.S + 255) / 256, 256, 0, stream>>>(f_b, idx_b, a.N, a.S, cf_ws, a.C * a.S);
        build_x_kernel<<<M / 256, 256, 0, stream>>>(p_b, f_b, ctr_b, cf_ws, nbr_b, a.N, a.S, a.C, M, x0);

        dim3 g1(M / 512, a.e / 16);
        conv_gemm_kernel<<<g1, 256, 0, stream>>>(a.Wa1, a.ba1, a.C + 3, 0, nullptr, x0, RA, M);
        in_stats_kernel<<<a.e, 256, 0, stream>>>(RA, M, mean_ws, rinv_ws);
        in_apply_kernel<<<dim3(M / 512, a.e), 256, 0, stream>>>(RA, M, mean_ws, rinv_ws);

        conv_gemm_kernel<<<g1, 256, 0, stream>>>(a.Wb1, a.bb1, a.e, 0, nullptr, RA, RB, M);
        maxk_kernel<<<(a.e * a.S + 255) / 256, 256, 0, stream>>>(RB, pooled, a.e * a.S);

        dim3 g2(M / 512, (2 * a.e) / 16);
        conv_gemm_kernel<<<g2, 256, 0, stream>>>(a.Wa2, a.ba2, 2 * a.e, a.e, pooled, RB, RC, M);
        in_stats_kernel<<<2 * a.e, 256, 0, stream>>>(RC, M, mean_ws, rinv_ws);
        in_apply_kernel<<<dim3(M / 512, 2 * a.e), 256, 0, stream>>>(RC, M, mean_ws, rinv_ws);

        conv_gemm_kernel<<<g1, 256, 0, stream>>>(a.Wb2, a.bb2, 2 * a.e, 0, nullptr, RC, RD, M);
        in_stats_kernel<<<a.e, 256, 0, stream>>>(RD, M, mean_ws, rinv_ws);
        maxk_out_in_kernel<<<(a.e * a.S + 255) / 256, 256, 0, stream>>>(RD, a.S, mean_ws, rinv_ws, outf_b, a.e * a.S);
    }
}

extern "C" void kernel_launch(void* const* d_in, const int* in_sizes, int n_in,
                              void* d_out, int out_size, void* d_ws, size_t ws_size,
                              hipStream_t stream) {
    const float* p    = (const float*)d_in[0];
    const float* f    = (const float*)d_in[1];
    const float* w1a1 = (const float*)d_in[2];
    const float* b1a1 = (const float*)d_in[3];
    const float* w1b1 = (const float*)d_in[4];
    const float* b1b1 = (const float*)d_in[5];
    const float* w1a2 = (const float*)d_in[6];
    const float* b1a2 = (const float*)d_in[7];
    const float* w1b2 = (const float*)d_in[8];
    const float* b1b2 = (const float*)d_in[9];
    const float* w2a1 = (const float*)d_in[10];
    const float* b2a1 = (const float*)d_in[11];
    const float* w2b1 = (const float*)d_in[12];
    const float* b2b1 = (const float*)d_in[13];
    const float* w2a2 = (const float*)d_in[14];
    const float* b2a2 = (const float*)d_in[15];
    const float* w2b2 = (const float*)d_in[16];
    const float* b2b2 = (const float*)d_in[17];

    float* out   = (float*)d_out;
    float* outp1 = out;                       // (4,2048,3)   = 24576
    float* outf1 = out + 24576;               // (4,192,2048) = 1572864
    float* outp2 = outf1 + 1572864;           // (4,512,3)    = 6144
    float* outf2 = outp2 + 6144;              // (4,384,512)  = 786432

    uint8_t* wsp = (uint8_t*)d_ws;
    uint8_t* wend = wsp + ws_size;
    auto alloc = [&](size_t bytes) -> void* {
        void* r = wsp;
        wsp += (bytes + 255) & ~(size_t)255;
        return r;
    };
    int*   idx1   = (int*)  alloc((size_t)4 * 2048 * 4);
    int*   idx2   = (int*)  alloc((size_t)4 * 512 * 4);
    int*   nbr1   = (int*)  alloc((size_t)4 * 2048 * K_NBR * 4);
    int*   nbr2   = (int*)  alloc((size_t)4 * 512 * K_NBR * 4);
    float* cf_ws  = (float*)alloc((size_t)192 * 512 * 4);
    float* mean_ws= (float*)alloc((size_t)768 * 4);
    float* rinv_ws= (float*)alloc((size_t)768 * 4);
    __half* pooled = (__half*)alloc((size_t)192 * 2048 * 2);
    if (wsp > wend) return;

    // geometry: verified-exact FPS arithmetic + frozen ball query
    fps_kernel<32><<<4, 256, 0, stream>>>(p, 8192, 2048, idx1, outp1);
    ball_query_kernel<<<(4 * 2048) / 4, 256, 0, stream>>>(p, outp1, 8192, 2048, nbr1);
    fps_kernel<8><<<4, 256, 0, stream>>>(outp1, 2048, 512, idx2, outp2);
    ball_query_kernel<<<(4 * 512) / 4, 256, 0, stream>>>(outp1, outp2, 2048, 512, nbr2);

    const size_t MB = (size_t)1024 * 1024;
    uint8_t* R1 = (uint8_t*)alloc(48 * MB);
    uint8_t* R2 = (uint8_t*)alloc(24 * MB);
    if (wsp > wend) return;

    StageArgs s1 { p, f, outp1, nbr1, idx1, 8192, 2048, 3, 192,
                   w1a1, b1a1, w1b1, b1b1, w1a2, b1a2, w1b2, b1b2, outf1 };
    StageArgs s2 { outp1, outf1, outp2, nbr2, idx2, 2048, 512, 192, 384,
                   w2a1, b2a1, w2b1, b2b1, w2a2, b2a2, w2b2, b2b2, outf2 };

    run_conv_stage(s1, stream, R1, R2, 8 * MB, pooled, cf_ws, mean_ws, rinv_ws);
    run_conv_stage(s2, stream, R1, R2, 8 * MB, pooled, cf_ws, mean_ws, rinv_ws);
}